// Round 5
// baseline (1265.309 us; speedup 1.0000x reference)
//
#include <hip/hip_runtime.h>
#include <hip/hip_bf16.h>

#define N_NODES 100000
#define E_EDGES 625000
#define D 128

// ---------------------------------------------------------------------------
// Kernel 1: h = x  (h lives in d_out, f32, vectorized copy)
// ---------------------------------------------------------------------------
__global__ void init_h(const float4* __restrict__ x, float4* __restrict__ h, int n4) {
    int g = blockIdx.x * 256 + threadIdx.x;
    if (g < n4) h[g] = x[g];
}

// ---------------------------------------------------------------------------
// Kernel 2: h[dst] += x[src] for every edge (atomic scatter-add).
// 32 threads per edge, 4 floats per thread (float4 load, 4 scalar atomics).
// Within a wave the edge id is uniform for each 32-lane half -> idx loads
// broadcast; x row reads are 512B contiguous (L3-resident).
// ---------------------------------------------------------------------------
__global__ void scatter_add(const float* __restrict__ x, const int* __restrict__ ei,
                            float* __restrict__ h) {
    long long g = (long long)blockIdx.x * 256 + threadIdx.x;
    if (g >= (long long)E_EDGES * 32) return;
    int e = (int)(g >> 5);
    int q = (int)(g & 31);
    int src = ei[e];
    int dst = ei[E_EDGES + e];
    float4 v = *(const float4*)&x[(long long)src * D + q * 4];
    float* p = &h[(long long)dst * D + q * 4];
    atomicAdd(p + 0, v.x);
    atomicAdd(p + 1, v.y);
    atomicAdd(p + 2, v.z);
    atomicAdd(p + 3, v.w);
}

// ---------------------------------------------------------------------------
// Kernel 3: out = relu(h @ W^T + b), in place (out == h).
// Block: 512 threads, BM=64 rows. W transposed into LDS (Wt[d][o], pad 132),
// h tile in LDS (pad 132). Thread computes 4 rows x 4 cols, K chunked by 4.
// Safe in-place: block stages its own rows to LDS before any write.
// ---------------------------------------------------------------------------
#define BM 64
__global__ __launch_bounds__(512) void gemm_relu(const float* __restrict__ h_in,
                                                 const float* __restrict__ W,
                                                 const float* __restrict__ b,
                                                 float* __restrict__ out, int n) {
    __shared__ float hs[BM][132];
    __shared__ float Wt[D][132];
    const int tid = threadIdx.x;
    const int row0 = blockIdx.x * BM;

    // stage W transposed: Wt[d][o] = W[o*D + d]
    for (int e = tid; e < D * D; e += 512) {
        int o = e >> 7, d = e & 127;
        Wt[d][o] = W[e];
    }
    // stage h rows (zero-pad past n)
    for (int e = tid; e < BM * D; e += 512) {
        int r = e >> 7, d = e & 127;
        int row = row0 + r;
        hs[r][d] = (row < n) ? h_in[(long long)row * D + d] : 0.0f;
    }
    __syncthreads();

    const int tr = tid >> 5;   // 0..15
    const int tc = tid & 31;   // 0..31
    const int c0 = 4 * tc;

    float acc[4][4] = {};
    for (int d0 = 0; d0 < D; d0 += 4) {
        float4 w0 = *(const float4*)&Wt[d0 + 0][c0];
        float4 w1 = *(const float4*)&Wt[d0 + 1][c0];
        float4 w2 = *(const float4*)&Wt[d0 + 2][c0];
        float4 w3 = *(const float4*)&Wt[d0 + 3][c0];
#pragma unroll
        for (int i = 0; i < 4; ++i) {
            float4 hh = *(const float4*)&hs[tr + 16 * i][d0];
            acc[i][0] += hh.x * w0.x + hh.y * w1.x + hh.z * w2.x + hh.w * w3.x;
            acc[i][1] += hh.x * w0.y + hh.y * w1.y + hh.z * w2.y + hh.w * w3.y;
            acc[i][2] += hh.x * w0.z + hh.y * w1.z + hh.z * w2.z + hh.w * w3.z;
            acc[i][3] += hh.x * w0.w + hh.y * w1.w + hh.z * w2.w + hh.w * w3.w;
        }
    }

    float4 bb = *(const float4*)&b[c0];
#pragma unroll
    for (int i = 0; i < 4; ++i) {
        int row = row0 + tr + 16 * i;
        if (row < n) {
            float4 o4;
            o4.x = fmaxf(acc[i][0] + bb.x, 0.0f);
            o4.y = fmaxf(acc[i][1] + bb.y, 0.0f);
            o4.z = fmaxf(acc[i][2] + bb.z, 0.0f);
            o4.w = fmaxf(acc[i][3] + bb.w, 0.0f);
            *(float4*)&out[(long long)row * D + c0] = o4;
        }
    }
}

extern "C" void kernel_launch(void* const* d_in, const int* in_sizes, int n_in,
                              void* d_out, int out_size, void* d_ws, size_t ws_size,
                              hipStream_t stream) {
    const float* x  = (const float*)d_in[0];
    const int*   ei = (const int*)d_in[1];
    const float* W  = (const float*)d_in[2];
    const float* b  = (const float*)d_in[3];
    float* out = (float*)d_out;

    // 1) h = x  (h aliased onto d_out)
    int n4 = N_NODES * D / 4;
    init_h<<<(n4 + 255) / 256, 256, 0, stream>>>((const float4*)x, (float4*)out, n4);

    // 2) h[dst] += x[src]
    long long sthreads = (long long)E_EDGES * 32;
    int sblocks = (int)((sthreads + 255) / 256);
    scatter_add<<<sblocks, 256, 0, stream>>>(x, ei, out);

    // 3) out = relu(h @ W^T + b), in place
    int gblocks = (N_NODES + BM - 1) / BM;
    gemm_relu<<<gblocks, 512, 0, stream>>>(out, W, b, out, N_NODES);
}

// Round 6
// 555.105 us; speedup vs baseline: 2.2794x; 2.2794x over previous
//
#include <hip/hip_runtime.h>
#include <hip/hip_bf16.h>

#define N_NODES 100000
#define E_EDGES 625000
#define D 128

// ---------------------------------------------------------------------------
// CSR workspace layout in d_ws (ints):
//   off[0 .. N]        start offsets (off[N] = E)
//   cur[0 .. N-1]      histogram counts, then running cursors during fill
//   bucket[0 .. E-1]   src indices binned by dst
// ---------------------------------------------------------------------------
#define OFF_OFS 0
#define CUR_OFS (N_NODES + 1)
#define BKT_OFS (2 * N_NODES + 1)
#define WS_INTS (2 * N_NODES + 1 + E_EDGES)

// ---- CSR build ------------------------------------------------------------
__global__ void hist_kernel(const int* __restrict__ ei, int* cnt) {
    int e = blockIdx.x * 256 + threadIdx.x;
    if (e < E_EDGES) atomicAdd(&cnt[ei[E_EDGES + e]], 1);
}

// exclusive scan of cnt[0..N-1] -> off[0..N-1]; off[N]=E; cur[i]=off[i].
// cnt and cur may alias (read-before-write per element, double-barriered).
__global__ __launch_bounds__(1024) void scan_kernel(const int* cnt, int* off, int* cur) {
    __shared__ int psum[1024];
    const int t = threadIdx.x;
    const int CH = (N_NODES + 1023) / 1024;  // 98
    int lo = t * CH;
    int hi = lo + CH < N_NODES ? lo + CH : N_NODES;
    int s = 0;
    for (int i = lo; i < hi; ++i) s += cnt[i];
    psum[t] = s;
    __syncthreads();
    if (t == 0) {
        int run = 0;
        for (int i = 0; i < 1024; ++i) { int v = psum[i]; psum[i] = run; run += v; }
    }
    __syncthreads();
    int run = psum[t];
    for (int i = lo; i < hi; ++i) {
        int v = cnt[i];          // read before cur[i] write (may alias)
        off[i] = run;
        cur[i] = run;
        run += v;
    }
    if (t == 0) off[N_NODES] = E_EDGES;
}

__global__ void fill_kernel(const int* __restrict__ ei, int* cur, int* __restrict__ bucket) {
    int e = blockIdx.x * 256 + threadIdx.x;
    if (e < E_EDGES) {
        int dst = ei[E_EDGES + e];
        int pos = atomicAdd(&cur[dst], 1);
        bucket[pos] = ei[e];  // src
    }
}

// ---- Gather-reduce: h[n] = x[n] + sum_{s in bucket[off[n]:off[n+1]]} x[s] --
// 32 lanes per node, float4 per lane (512B contiguous row reads, L3-resident).
__global__ __launch_bounds__(256) void gather_kernel(const float* __restrict__ x,
                                                     const int* __restrict__ off,
                                                     const int* __restrict__ bucket,
                                                     float* __restrict__ h) {
    int node = blockIdx.x * 8 + (threadIdx.x >> 5);
    if (node >= N_NODES) return;
    int q = threadIdx.x & 31;
    const float4* x4 = (const float4*)x;
    float4 acc = x4[node * 32 + q];
    int beg = off[node], end = off[node + 1];
    for (int j = beg; j < end; ++j) {
        int s = bucket[j];               // uniform across half-wave: broadcast
        float4 v = x4[s * 32 + q];
        acc.x += v.x; acc.y += v.y; acc.z += v.z; acc.w += v.w;
    }
    ((float4*)h)[node * 32 + q] = acc;
}

// ---- Fallback path (proven round-5): init + atomic scatter ----------------
__global__ void init_h(const float4* __restrict__ x, float4* __restrict__ h, int n4) {
    int g = blockIdx.x * 256 + threadIdx.x;
    if (g < n4) h[g] = x[g];
}

__global__ void scatter_add(const float* __restrict__ x, const int* __restrict__ ei,
                            float* __restrict__ h) {
    long long g = (long long)blockIdx.x * 256 + threadIdx.x;
    if (g >= (long long)E_EDGES * 32) return;
    int e = (int)(g >> 5);
    int q = (int)(g & 31);
    int src = ei[e];
    int dst = ei[E_EDGES + e];
    float4 v = *(const float4*)&x[(long long)src * D + q * 4];
    float* p = &h[(long long)dst * D + q * 4];
    atomicAdd(p + 0, v.x);
    atomicAdd(p + 1, v.y);
    atomicAdd(p + 2, v.z);
    atomicAdd(p + 3, v.w);
}

// ---------------------------------------------------------------------------
// GEMM+ReLU unchanged from round 5 (known-correct; rebuild next round with
// counters in hand — suspected 1-block/CU occupancy from 101KB LDS).
// ---------------------------------------------------------------------------
#define BM 64
__global__ __launch_bounds__(512) void gemm_relu(const float* __restrict__ h_in,
                                                 const float* __restrict__ W,
                                                 const float* __restrict__ b,
                                                 float* __restrict__ out, int n) {
    __shared__ float hs[BM][132];
    __shared__ float Wt[D][132];
    const int tid = threadIdx.x;
    const int row0 = blockIdx.x * BM;

    for (int e = tid; e < D * D; e += 512) {
        int o = e >> 7, d = e & 127;
        Wt[d][o] = W[e];
    }
    for (int e = tid; e < BM * D; e += 512) {
        int r = e >> 7, d = e & 127;
        int row = row0 + r;
        hs[r][d] = (row < n) ? h_in[(long long)row * D + d] : 0.0f;
    }
    __syncthreads();

    const int tr = tid >> 5;
    const int tc = tid & 31;
    const int c0 = 4 * tc;

    float acc[4][4] = {};
    for (int d0 = 0; d0 < D; d0 += 4) {
        float4 w0 = *(const float4*)&Wt[d0 + 0][c0];
        float4 w1 = *(const float4*)&Wt[d0 + 1][c0];
        float4 w2 = *(const float4*)&Wt[d0 + 2][c0];
        float4 w3 = *(const float4*)&Wt[d0 + 3][c0];
#pragma unroll
        for (int i = 0; i < 4; ++i) {
            float4 hh = *(const float4*)&hs[tr + 16 * i][d0];
            acc[i][0] += hh.x * w0.x + hh.y * w1.x + hh.z * w2.x + hh.w * w3.x;
            acc[i][1] += hh.x * w0.y + hh.y * w1.y + hh.z * w2.y + hh.w * w3.y;
            acc[i][2] += hh.x * w0.z + hh.y * w1.z + hh.z * w2.z + hh.w * w3.z;
            acc[i][3] += hh.x * w0.w + hh.y * w1.w + hh.z * w2.w + hh.w * w3.w;
        }
    }

    float4 bb = *(const float4*)&b[c0];
#pragma unroll
    for (int i = 0; i < 4; ++i) {
        int row = row0 + tr + 16 * i;
        if (row < n) {
            float4 o4;
            o4.x = fmaxf(acc[i][0] + bb.x, 0.0f);
            o4.y = fmaxf(acc[i][1] + bb.y, 0.0f);
            o4.z = fmaxf(acc[i][2] + bb.z, 0.0f);
            o4.w = fmaxf(acc[i][3] + bb.w, 0.0f);
            *(float4*)&out[(long long)row * D + c0] = o4;
        }
    }
}

extern "C" void kernel_launch(void* const* d_in, const int* in_sizes, int n_in,
                              void* d_out, int out_size, void* d_ws, size_t ws_size,
                              hipStream_t stream) {
    const float* x  = (const float*)d_in[0];
    const int*   ei = (const int*)d_in[1];
    const float* W  = (const float*)d_in[2];
    const float* b  = (const float*)d_in[3];
    float* out = (float*)d_out;

    if (ws_size >= (size_t)WS_INTS * sizeof(int)) {
        int* wsi = (int*)d_ws;
        int eblocks = (E_EDGES + 255) / 256;
        hipMemsetAsync(wsi + CUR_OFS, 0, N_NODES * sizeof(int), stream);
        hist_kernel<<<eblocks, 256, 0, stream>>>(ei, wsi + CUR_OFS);
        scan_kernel<<<1, 1024, 0, stream>>>(wsi + CUR_OFS, wsi + OFF_OFS, wsi + CUR_OFS);
        fill_kernel<<<eblocks, 256, 0, stream>>>(ei, wsi + CUR_OFS, wsi + BKT_OFS);
        int gblocks = (N_NODES + 7) / 8;
        gather_kernel<<<gblocks, 256, 0, stream>>>(x, wsi + OFF_OFS, wsi + BKT_OFS, out);
    } else {
        // fallback: proven atomic path
        int n4 = N_NODES * D / 4;
        init_h<<<(n4 + 255) / 256, 256, 0, stream>>>((const float4*)x, (float4*)out, n4);
        long long sthreads = (long long)E_EDGES * 32;
        int sblocks = (int)((sthreads + 255) / 256);
        scatter_add<<<sblocks, 256, 0, stream>>>(x, ei, out);
    }

    int mblocks = (N_NODES + BM - 1) / BM;
    gemm_relu<<<mblocks, 512, 0, stream>>>(out, W, b, out, N_NODES);
}

// Round 7
// 325.850 us; speedup vs baseline: 3.8831x; 1.7036x over previous
//
#include <hip/hip_runtime.h>
#include <hip/hip_bf16.h>

#define N_NODES 100000
#define E_EDGES 625000
#define D 128

// ---------------------------------------------------------------------------
// CSR workspace layout in d_ws (ints), all regions 16B-aligned:
//   off[0 .. N]     node start offsets (off[N] = E)      @ OFF_OFS
//   cnt/cur[0..N-1] histogram counts -> fill cursors     @ CUR_OFS
//   bucket[0..E-1]  src indices binned by dst            @ BKT_OFS
//   bsum[0..48]     per-block partial sums for the scan  @ BSM_OFS
// ---------------------------------------------------------------------------
#define OFF_OFS 0
#define CUR_OFS 100004                    // (N+1) padded to %4 -> 16B aligned
#define BKT_OFS (CUR_OFS + N_NODES)      // 200004, 16B aligned
#define BSM_OFS (BKT_OFS + E_EDGES)      // 825004
#define WS_INTS (BSM_OFS + 64)

#define SCAN_CHUNK 2048
#define SCAN_BLOCKS ((N_NODES + SCAN_CHUNK - 1) / SCAN_CHUNK)  // 49

// ---- CSR build ------------------------------------------------------------
__global__ void hist_kernel(const int* __restrict__ ei, int* cnt) {
    int e = blockIdx.x * 256 + threadIdx.x;
    if (e < E_EDGES) atomicAdd(&cnt[ei[E_EDGES + e]], 1);
}

// k1: per-block sums of cnt chunks
__global__ __launch_bounds__(256) void scan_partial(const int* __restrict__ cnt,
                                                    int* __restrict__ bsum) {
    __shared__ int wsum[4];
    const int b = blockIdx.x, t = threadIdx.x;
    const int base = b * SCAN_CHUNK + t * 8;
    int s = 0;
#pragma unroll
    for (int k = 0; k < 8; ++k) {
        int i = base + k;
        if (i < N_NODES) s += cnt[i];
    }
    for (int d = 32; d > 0; d >>= 1) s += __shfl_xor(s, d);
    if ((t & 63) == 0) wsum[t >> 6] = s;
    __syncthreads();
    if (t == 0) bsum[b] = wsum[0] + wsum[1] + wsum[2] + wsum[3];
}

// k2: exclusive scan of the 49 block sums in one wave; also set off[N]=E
__global__ void scan_bsums(int* bsum, int* off) {
    int t = threadIdx.x;  // 64 threads
    int orig = (t < SCAN_BLOCKS) ? bsum[t] : 0;
    int v = orig;
    for (int d = 1; d < 64; d <<= 1) {
        int u = __shfl_up(v, d);
        if (t >= d) v += u;
    }
    if (t < SCAN_BLOCKS) bsum[t] = v - orig;  // exclusive
    if (t == 0) off[N_NODES] = E_EDGES;
}

// k3: full exclusive scan, writes off[] and cur[] (cur aliases cnt — each
// thread reads its 8 elements into registers before writing them back)
__global__ __launch_bounds__(256) void scan_final(const int* __restrict__ cnt,
                                                  const int* __restrict__ bsum,
                                                  int* __restrict__ off,
                                                  int* __restrict__ cur) {
    __shared__ int woff[4];
    const int b = blockIdx.x, t = threadIdx.x;
    const int w = t >> 6, lane = t & 63;
    const int base = b * SCAN_CHUNK + t * 8;
    int v[8];
    int s = 0;
#pragma unroll
    for (int k = 0; k < 8; ++k) {
        int i = base + k;
        v[k] = (i < N_NODES) ? cnt[i] : 0;
        s += v[k];
    }
    int inc = s;
    for (int d = 1; d < 64; d <<= 1) {
        int u = __shfl_up(inc, d);
        if (lane >= d) inc += u;
    }
    if (lane == 63) woff[w] = inc;
    __syncthreads();
    if (t == 0) {
        int run = 0;
        for (int i = 0; i < 4; ++i) { int x = woff[i]; woff[i] = run; run += x; }
    }
    __syncthreads();
    int prefix = bsum[b] + woff[w] + (inc - s);
#pragma unroll
    for (int k = 0; k < 8; ++k) {
        int i = base + k;
        if (i < N_NODES) { off[i] = prefix; cur[i] = prefix; prefix += v[k]; }
    }
}

__global__ void fill_kernel(const int* __restrict__ ei, int* cur, int* __restrict__ bucket) {
    int e = blockIdx.x * 256 + threadIdx.x;
    if (e < E_EDGES) {
        int dst = ei[E_EDGES + e];
        int pos = atomicAdd(&cur[dst], 1);
        bucket[pos] = ei[e];  // src
    }
}

// ---- Gather-reduce: h[n] = x[n] + sum_{s in bucket[off[n]:off[n+1]]} x[s] --
__global__ __launch_bounds__(256) void gather_kernel(const float* __restrict__ x,
                                                     const int* __restrict__ off,
                                                     const int* __restrict__ bucket,
                                                     float* __restrict__ h) {
    int node = blockIdx.x * 8 + (threadIdx.x >> 5);
    if (node >= N_NODES) return;
    int q = threadIdx.x & 31;
    const float4* x4 = (const float4*)x;
    float4 acc = x4[node * 32 + q];
    int beg = off[node], end = off[node + 1];
    for (int j = beg; j < end; ++j) {
        int s = bucket[j];               // uniform across half-wave: broadcast
        float4 v = x4[s * 32 + q];
        acc.x += v.x; acc.y += v.y; acc.z += v.z; acc.w += v.w;
    }
    ((float4*)h)[node * 32 + q] = acc;
}

// ---- Fallback path (proven round-5): init + atomic scatter ----------------
__global__ void init_h(const float4* __restrict__ x, float4* __restrict__ h, int n4) {
    int g = blockIdx.x * 256 + threadIdx.x;
    if (g < n4) h[g] = x[g];
}

__global__ void scatter_add(const float* __restrict__ x, const int* __restrict__ ei,
                            float* __restrict__ h) {
    long long g = (long long)blockIdx.x * 256 + threadIdx.x;
    if (g >= (long long)E_EDGES * 32) return;
    int e = (int)(g >> 5);
    int q = (int)(g & 31);
    int src = ei[e];
    int dst = ei[E_EDGES + e];
    float4 v = *(const float4*)&x[(long long)src * D + q * 4];
    float* p = &h[(long long)dst * D + q * 4];
    atomicAdd(p + 0, v.x);
    atomicAdd(p + 1, v.y);
    atomicAdd(p + 2, v.z);
    atomicAdd(p + 3, v.w);
}

// ---------------------------------------------------------------------------
// GEMM+ReLU unchanged (known-correct; rebuild once its counters are visible).
// ---------------------------------------------------------------------------
#define BM 64
__global__ __launch_bounds__(512) void gemm_relu(const float* __restrict__ h_in,
                                                 const float* __restrict__ W,
                                                 const float* __restrict__ b,
                                                 float* __restrict__ out, int n) {
    __shared__ float hs[BM][132];
    __shared__ float Wt[D][132];
    const int tid = threadIdx.x;
    const int row0 = blockIdx.x * BM;

    for (int e = tid; e < D * D; e += 512) {
        int o = e >> 7, d = e & 127;
        Wt[d][o] = W[e];
    }
    for (int e = tid; e < BM * D; e += 512) {
        int r = e >> 7, d = e & 127;
        int row = row0 + r;
        hs[r][d] = (row < n) ? h_in[(long long)row * D + d] : 0.0f;
    }
    __syncthreads();

    const int tr = tid >> 5;
    const int tc = tid & 31;
    const int c0 = 4 * tc;

    float acc[4][4] = {};
    for (int d0 = 0; d0 < D; d0 += 4) {
        float4 w0 = *(const float4*)&Wt[d0 + 0][c0];
        float4 w1 = *(const float4*)&Wt[d0 + 1][c0];
        float4 w2 = *(const float4*)&Wt[d0 + 2][c0];
        float4 w3 = *(const float4*)&Wt[d0 + 3][c0];
#pragma unroll
        for (int i = 0; i < 4; ++i) {
            float4 hh = *(const float4*)&hs[tr + 16 * i][d0];
            acc[i][0] += hh.x * w0.x + hh.y * w1.x + hh.z * w2.x + hh.w * w3.x;
            acc[i][1] += hh.x * w0.y + hh.y * w1.y + hh.z * w2.y + hh.w * w3.y;
            acc[i][2] += hh.x * w0.z + hh.y * w1.z + hh.z * w2.z + hh.w * w3.z;
            acc[i][3] += hh.x * w0.w + hh.y * w1.w + hh.z * w2.w + hh.w * w3.w;
        }
    }

    float4 bb = *(const float4*)&b[c0];
#pragma unroll
    for (int i = 0; i < 4; ++i) {
        int row = row0 + tr + 16 * i;
        if (row < n) {
            float4 o4;
            o4.x = fmaxf(acc[i][0] + bb.x, 0.0f);
            o4.y = fmaxf(acc[i][1] + bb.y, 0.0f);
            o4.z = fmaxf(acc[i][2] + bb.z, 0.0f);
            o4.w = fmaxf(acc[i][3] + bb.w, 0.0f);
            *(float4*)&out[(long long)row * D + c0] = o4;
        }
    }
}

extern "C" void kernel_launch(void* const* d_in, const int* in_sizes, int n_in,
                              void* d_out, int out_size, void* d_ws, size_t ws_size,
                              hipStream_t stream) {
    const float* x  = (const float*)d_in[0];
    const int*   ei = (const int*)d_in[1];
    const float* W  = (const float*)d_in[2];
    const float* b  = (const float*)d_in[3];
    float* out = (float*)d_out;

    if (ws_size >= (size_t)WS_INTS * sizeof(int)) {
        int* wsi = (int*)d_ws;
        int eblocks = (E_EDGES + 255) / 256;
        hipMemsetAsync(wsi + CUR_OFS, 0, N_NODES * sizeof(int), stream);
        hist_kernel<<<eblocks, 256, 0, stream>>>(ei, wsi + CUR_OFS);
        scan_partial<<<SCAN_BLOCKS, 256, 0, stream>>>(wsi + CUR_OFS, wsi + BSM_OFS);
        scan_bsums<<<1, 64, 0, stream>>>(wsi + BSM_OFS, wsi + OFF_OFS);
        scan_final<<<SCAN_BLOCKS, 256, 0, stream>>>(wsi + CUR_OFS, wsi + BSM_OFS,
                                                    wsi + OFF_OFS, wsi + CUR_OFS);
        fill_kernel<<<eblocks, 256, 0, stream>>>(ei, wsi + CUR_OFS, wsi + BKT_OFS);
        int gblocks = (N_NODES + 7) / 8;
        gather_kernel<<<gblocks, 256, 0, stream>>>(x, wsi + OFF_OFS, wsi + BKT_OFS, out);
    } else {
        // fallback: proven atomic path
        int n4 = N_NODES * D / 4;
        init_h<<<(n4 + 255) / 256, 256, 0, stream>>>((const float4*)x, (float4*)out, n4);
        long long sthreads = (long long)E_EDGES * 32;
        int sblocks = (int)((sthreads + 255) / 256);
        scatter_add<<<sblocks, 256, 0, stream>>>(x, ei, out);
    }

    int mblocks = (N_NODES + BM - 1) / BM;
    gemm_relu<<<mblocks, 512, 0, stream>>>(out, W, b, out, N_NODES);
}

// Round 8
// 248.225 us; speedup vs baseline: 5.0974x; 1.3127x over previous
//
#include <hip/hip_runtime.h>
#include <hip/hip_bf16.h>

#define N_NODES 100000
#define E_EDGES 625000
#define D 128

// ---------------------------------------------------------------------------
// CSR workspace layout in d_ws (ints), all regions 16B-aligned:
//   off[0 .. N]     node start offsets (off[N] = E)      @ OFF_OFS
//   cnt/cur[0..N-1] histogram counts -> fill cursors     @ CUR_OFS
//   bucket[0..E-1]  src indices binned by dst            @ BKT_OFS
//   bsum[0..48]     per-block partial sums for the scan  @ BSM_OFS
// ---------------------------------------------------------------------------
#define OFF_OFS 0
#define CUR_OFS 100004
#define BKT_OFS (CUR_OFS + N_NODES)
#define BSM_OFS (BKT_OFS + E_EDGES)
#define WS_INTS (BSM_OFS + 64)

#define SCAN_CHUNK 2048
#define SCAN_BLOCKS ((N_NODES + SCAN_CHUNK - 1) / SCAN_CHUNK)  // 49

typedef short s16x8 __attribute__((ext_vector_type(8)));     // 8 bf16 (4 VGPRs)
typedef unsigned short us8 __attribute__((ext_vector_type(8)));
typedef float f32x4 __attribute__((ext_vector_type(4)));

// f32 -> bf16 round-to-nearest-even (finite inputs)
static __device__ __forceinline__ unsigned short f2bf(float f) {
    unsigned int u = __builtin_bit_cast(unsigned int, f);
    u += 0x7fffu + ((u >> 16) & 1u);
    return (unsigned short)(u >> 16);
}

// ---- CSR build ------------------------------------------------------------
__global__ void hist_kernel(const int* __restrict__ ei, int* cnt) {
    int e = blockIdx.x * 256 + threadIdx.x;
    if (e < E_EDGES) atomicAdd(&cnt[ei[E_EDGES + e]], 1);
}

__global__ __launch_bounds__(256) void scan_partial(const int* __restrict__ cnt,
                                                    int* __restrict__ bsum) {
    __shared__ int wsum[4];
    const int b = blockIdx.x, t = threadIdx.x;
    const int base = b * SCAN_CHUNK + t * 8;
    int s = 0;
#pragma unroll
    for (int k = 0; k < 8; ++k) {
        int i = base + k;
        if (i < N_NODES) s += cnt[i];
    }
    for (int d = 32; d > 0; d >>= 1) s += __shfl_xor(s, d);
    if ((t & 63) == 0) wsum[t >> 6] = s;
    __syncthreads();
    if (t == 0) bsum[b] = wsum[0] + wsum[1] + wsum[2] + wsum[3];
}

__global__ void scan_bsums(int* bsum, int* off) {
    int t = threadIdx.x;  // 64
    int orig = (t < SCAN_BLOCKS) ? bsum[t] : 0;
    int v = orig;
    for (int d = 1; d < 64; d <<= 1) {
        int u = __shfl_up(v, d);
        if (t >= d) v += u;
    }
    if (t < SCAN_BLOCKS) bsum[t] = v - orig;
    if (t == 0) off[N_NODES] = E_EDGES;
}

__global__ __launch_bounds__(256) void scan_final(const int* __restrict__ cnt,
                                                  const int* __restrict__ bsum,
                                                  int* __restrict__ off,
                                                  int* __restrict__ cur) {
    __shared__ int woff[4];
    const int b = blockIdx.x, t = threadIdx.x;
    const int w = t >> 6, lane = t & 63;
    const int base = b * SCAN_CHUNK + t * 8;
    int v[8];
    int s = 0;
#pragma unroll
    for (int k = 0; k < 8; ++k) {
        int i = base + k;
        v[k] = (i < N_NODES) ? cnt[i] : 0;
        s += v[k];
    }
    int inc = s;
    for (int d = 1; d < 64; d <<= 1) {
        int u = __shfl_up(inc, d);
        if (lane >= d) inc += u;
    }
    if (lane == 63) woff[w] = inc;
    __syncthreads();
    if (t == 0) {
        int run = 0;
        for (int i = 0; i < 4; ++i) { int x = woff[i]; woff[i] = run; run += x; }
    }
    __syncthreads();
    int prefix = bsum[b] + woff[w] + (inc - s);
#pragma unroll
    for (int k = 0; k < 8; ++k) {
        int i = base + k;
        if (i < N_NODES) { off[i] = prefix; cur[i] = prefix; prefix += v[k]; }
    }
}

__global__ void fill_kernel(const int* __restrict__ ei, int* cur, int* __restrict__ bucket) {
    int e = blockIdx.x * 256 + threadIdx.x;
    if (e < E_EDGES) {
        int dst = ei[E_EDGES + e];
        int pos = atomicAdd(&cur[dst], 1);
        bucket[pos] = ei[e];
    }
}

// ---- Gather-reduce: h[n] = x[n] + sum_{s in bucket[off[n]:off[n+1]]} x[s] --
__global__ __launch_bounds__(256) void gather_kernel(const float* __restrict__ x,
                                                     const int* __restrict__ off,
                                                     const int* __restrict__ bucket,
                                                     float* __restrict__ h) {
    int node = blockIdx.x * 8 + (threadIdx.x >> 5);
    if (node >= N_NODES) return;
    int q = threadIdx.x & 31;
    const float4* x4 = (const float4*)x;
    float4 acc = x4[node * 32 + q];
    int beg = off[node], end = off[node + 1];
    for (int j = beg; j < end; ++j) {
        int s = bucket[j];
        float4 v = x4[s * 32 + q];
        acc.x += v.x; acc.y += v.y; acc.z += v.z; acc.w += v.w;
    }
    ((float4*)h)[node * 32 + q] = acc;
}

// ---- Fallback path: init + atomic scatter ---------------------------------
__global__ void init_h(const float4* __restrict__ x, float4* __restrict__ h, int n4) {
    int g = blockIdx.x * 256 + threadIdx.x;
    if (g < n4) h[g] = x[g];
}

__global__ void scatter_add(const float* __restrict__ x, const int* __restrict__ ei,
                            float* __restrict__ h) {
    long long g = (long long)blockIdx.x * 256 + threadIdx.x;
    if (g >= (long long)E_EDGES * 32) return;
    int e = (int)(g >> 5);
    int q = (int)(g & 31);
    int src = ei[e];
    int dst = ei[E_EDGES + e];
    float4 v = *(const float4*)&x[(long long)src * D + q * 4];
    float* p = &h[(long long)dst * D + q * 4];
    atomicAdd(p + 0, v.x);
    atomicAdd(p + 1, v.y);
    atomicAdd(p + 2, v.z);
    atomicAdd(p + 3, v.w);
}

// ---------------------------------------------------------------------------
// GEMM+ReLU via bf16 MFMA (m97 "gemm_bt" structure; W is natively B^T).
// 256 thr / 4 waves (2x2), BM=64, out tile 64x128, in place (stages rows to
// LDS before overwrite). LDS: hA 16KB + wB 32KB = 48KB -> 3 blocks/CU.
// XOR swizzle byte ^= (row&15)<<4 balances all 32 banks for ds_read_b128.
// A/B frag: row=lane&15, k=(lane>>4)*8+j. C/D: col=lane&15, row=(lane>>4)*4+r.
// ---------------------------------------------------------------------------
#define BM 64
__global__ __launch_bounds__(256) void gemm_relu_mfma(const float* __restrict__ h_in,
                                                      const float* __restrict__ W,
                                                      const float* __restrict__ bias,
                                                      float* __restrict__ out, int n) {
    __shared__ unsigned short hA[BM * D];   // 16 KB, swizzled
    __shared__ unsigned short wB[D * D];    // 32 KB, swizzled
    const int tid = threadIdx.x;
    const int row0 = blockIdx.x * BM;

    // stage h tile: 1024 chunks of 8 f32 -> 8 bf16 (16B ds_write_b128)
    for (int c = tid; c < BM * D / 8; c += 256) {
        int r = c >> 4, ch = c & 15;
        int grow = row0 + r;
        us8 o = {};
        if (grow < n) {
            const float4* p = (const float4*)&h_in[(size_t)grow * D + ch * 8];
            float4 p0 = p[0], p1 = p[1];
            o[0] = f2bf(p0.x); o[1] = f2bf(p0.y); o[2] = f2bf(p0.z); o[3] = f2bf(p0.w);
            o[4] = f2bf(p1.x); o[5] = f2bf(p1.y); o[6] = f2bf(p1.z); o[7] = f2bf(p1.w);
        }
        unsigned int byte = (unsigned)(r * 256 + ch * 16) ^ ((r & 15) << 4);
        *(us8*)&hA[byte >> 1] = o;
    }
    // stage W tile: 2048 chunks
    for (int c = tid; c < D * D / 8; c += 256) {
        int r = c >> 4, ch = c & 15;
        const float4* p = (const float4*)&W[(size_t)r * D + ch * 8];
        float4 p0 = p[0], p1 = p[1];
        us8 o;
        o[0] = f2bf(p0.x); o[1] = f2bf(p0.y); o[2] = f2bf(p0.z); o[3] = f2bf(p0.w);
        o[4] = f2bf(p1.x); o[5] = f2bf(p1.y); o[6] = f2bf(p1.z); o[7] = f2bf(p1.w);
        unsigned int byte = (unsigned)(r * 256 + ch * 16) ^ ((r & 15) << 4);
        *(us8*)&wB[byte >> 1] = o;
    }
    __syncthreads();

    const int w = tid >> 6, lane = tid & 63;
    const int wr = (w >> 1) * 32;       // wave row offset (0/32)
    const int wc = (w & 1) * 64;        // wave col offset (0/64)
    const int lr = lane & 15;
    const int kb = (lane >> 4) * 8;     // k sub-offset 0/8/16/24

    f32x4 acc[2][4] = {};
    for (int k0 = 0; k0 < D; k0 += 32) {
        s16x8 af[2], bf[4];
#pragma unroll
        for (int m = 0; m < 2; ++m) {
            int r = wr + m * 16 + lr;
            unsigned int byte = (unsigned)(r * 256 + (k0 + kb) * 2) ^ ((r & 15) << 4);
            af[m] = *(s16x8*)&hA[byte >> 1];
        }
#pragma unroll
        for (int nn = 0; nn < 4; ++nn) {
            int o = wc + nn * 16 + lr;
            unsigned int byte = (unsigned)(o * 256 + (k0 + kb) * 2) ^ ((o & 15) << 4);
            bf[nn] = *(s16x8*)&wB[byte >> 1];
        }
#pragma unroll
        for (int m = 0; m < 2; ++m)
#pragma unroll
            for (int nn = 0; nn < 4; ++nn)
                acc[m][nn] = __builtin_amdgcn_mfma_f32_16x16x32_bf16(af[m], bf[nn],
                                                                     acc[m][nn], 0, 0, 0);
    }

    const int cr4 = (lane >> 4) * 4;
#pragma unroll
    for (int m = 0; m < 2; ++m) {
#pragma unroll
        for (int r = 0; r < 4; ++r) {
            int grow = row0 + wr + m * 16 + cr4 + r;
            if (grow < n) {
#pragma unroll
                for (int nn = 0; nn < 4; ++nn) {
                    int col = wc + nn * 16 + (lane & 15);
                    float v = acc[m][nn][r] + bias[col];
                    out[(size_t)grow * D + col] = fmaxf(v, 0.0f);
                }
            }
        }
    }
}

extern "C" void kernel_launch(void* const* d_in, const int* in_sizes, int n_in,
                              void* d_out, int out_size, void* d_ws, size_t ws_size,
                              hipStream_t stream) {
    const float* x  = (const float*)d_in[0];
    const int*   ei = (const int*)d_in[1];
    const float* W  = (const float*)d_in[2];
    const float* b  = (const float*)d_in[3];
    float* out = (float*)d_out;

    if (ws_size >= (size_t)WS_INTS * sizeof(int)) {
        int* wsi = (int*)d_ws;
        int eblocks = (E_EDGES + 255) / 256;
        hipMemsetAsync(wsi + CUR_OFS, 0, N_NODES * sizeof(int), stream);
        hist_kernel<<<eblocks, 256, 0, stream>>>(ei, wsi + CUR_OFS);
        scan_partial<<<SCAN_BLOCKS, 256, 0, stream>>>(wsi + CUR_OFS, wsi + BSM_OFS);
        scan_bsums<<<1, 64, 0, stream>>>(wsi + BSM_OFS, wsi + OFF_OFS);
        scan_final<<<SCAN_BLOCKS, 256, 0, stream>>>(wsi + CUR_OFS, wsi + BSM_OFS,
                                                    wsi + OFF_OFS, wsi + CUR_OFS);
        fill_kernel<<<eblocks, 256, 0, stream>>>(ei, wsi + CUR_OFS, wsi + BKT_OFS);
        int gblocks = (N_NODES + 7) / 8;
        gather_kernel<<<gblocks, 256, 0, stream>>>(x, wsi + OFF_OFS, wsi + BKT_OFS, out);
    } else {
        int n4 = N_NODES * D / 4;
        init_h<<<(n4 + 255) / 256, 256, 0, stream>>>((const float4*)x, (float4*)out, n4);
        long long sthreads = (long long)E_EDGES * 32;
        int sblocks = (int)((sthreads + 255) / 256);
        scatter_add<<<sblocks, 256, 0, stream>>>(x, ei, out);
    }

    int mblocks = (N_NODES + BM - 1) / BM;
    gemm_relu_mfma<<<mblocks, 256, 0, stream>>>(out, W, b, out, N_NODES);
}